// Round 3
// baseline (185.546 us; speedup 1.0000x reference)
//
#include <hip/hip_runtime.h>
#include <hip/hip_fp16.h>
#include <cstdint>

// ---------------------------------------------------------------------------
// SingleDeformConv on MI355X (gfx950)
// data (8,64,128,128) f32; w (64,64,3,3); b (64); w_off (18,64,3,3); b_off(18);
// w_mod (9,64,3,3); b_mod (9).  out = relu(deform_conv(...)) (8,64,128,128) f32
//
// R13 -> R14: LDS-window gathers. R13 showed the tap gathers are TA/L1
// throughput-bound: 64-lane dwordx4 gathers where every lane hits a distinct
// 128-B line => ~64 L1 lookups/instr, ~50-60 us of TA serialization (MFMA 7%).
// Fix: stage a 5-row x 68-col window of xt (43.5 KB, covers all clamped
// corners when |offset|<1) in LDS once per block; do the 72 scattered corner
// reads as ds_read_b128 (structural ~12cyc vs ~64cyc TA). Params phase
// window-tests each clamped corner and encodes u16 = window-idx (fast) or
// 0x8000|pos (slow); __all-guarded fast path, global-gather fallback keeps
// correctness for arbitrary offsets. conv27's zero-padded halo is a subset of
// the window -> R13's separate tile27 staging deleted (fusion now ~free).
// Window chunks XOR-swizzled by (cc&7). LDS 75776 B dynamic (2 blocks/CU).
// ---------------------------------------------------------------------------

typedef _Float16 half8 __attribute__((ext_vector_type(8)));
typedef __attribute__((ext_vector_type(4))) float floatx4;

// pack two floats -> f16x2 dword (RNE)
__device__ __forceinline__ unsigned int pack2h(float lo, float hi) {
    __half2 h = __floats2half2_rn(lo, hi);
    union { __half2 h; unsigned int u; } cv; cv.h = h;
    return cv.u;
}
// blend one f16x2 dword from 4 corners with broadcast __half2 weights
__device__ __forceinline__ unsigned int blend2h(unsigned int a, unsigned int b,
                                                unsigned int c, unsigned int d,
                                                const __half2* w) {
    union { unsigned int u; __half2 h; } A, B, C, D, O;
    A.u = a; B.u = b; C.u = c; D.u = d;
    __half2 s = __hmul2(A.h, w[0]);
    s = __hfma2(B.h, w[1], s);
    s = __hfma2(C.h, w[2], s);
    s = __hfma2(D.h, w[3], s);
    O.h = s;
    return O.u;
}

// Workspace layout (bytes)
#define OFF_DATAT 0u               // [8][16384][64] f16   = 16777216 B
#define OFF_WM    16777216u        // [64][576] f16        = 73728 B
#define OFF_W27   16850944u        // [32][576] f16        = 36864 B
#define OFF_B27   16887808u        // [32] f32             = 128 B
// total 16887936 B

// LDS layout (dynamic, 75776 B):
//   win  [5][68] rows of 128 B (64ch f16, chunk-swizzled by cc&7)  @0  43520
//   samp [2][64][72] f16  @43520  18432   (pp[64][28] f32 overlays @43520)
//   pOff [576] ushort4    @61952   4608
//   pW   [576] uint4      @66560   9216
#define L_SAMP 43520
#define L_POFF 61952
#define L_PW   66560
#define L_TOTAL 75776

// ---------------------------------------------------------------------------
// Kernel 1: prep = NCHW f32 -> NHWC f16 transpose (blocks 0..2047)
//           + weight packing / bias27 (blocks 2048..2263)
// ---------------------------------------------------------------------------
__global__ __launch_bounds__(256) void prep_k(const float* __restrict__ x,
                                              unsigned short* __restrict__ xt,
                                              const float* __restrict__ w,
                                              const float* __restrict__ w_off,
                                              const float* __restrict__ w_mod,
                                              const float* __restrict__ b_off,
                                              const float* __restrict__ b_mod,
                                              unsigned short* __restrict__ wpackM,
                                              unsigned short* __restrict__ wpack27,
                                              float* __restrict__ bias27) {
    __shared__ float tile[64][65];
    int blk = blockIdx.x;
    if (blk < 2048) {                              // ---- transpose ----
        int b    = blk >> 8;
        int pos0 = (blk & 255) << 6;
        int lane = threadIdx.x & 63;
        int g    = threadIdx.x >> 6;
        for (int c = g; c < 64; c += 4)
            tile[c][lane] = x[(((b << 6) + c) << 14) + pos0 + lane];
        __syncthreads();
        int c2 = lane & 31;
        for (int i = g; i < 32; i += 4) {
            int pr = (i << 1) + (lane >> 5);
            unsigned int d = pack2h(tile[c2 << 1][pr], tile[(c2 << 1) + 1][pr]);
            *(unsigned int*)&xt[((size_t)((b << 14) + pos0 + pr) << 6) + (c2 << 1)] = d;
        }
        return;
    }
    // ---- weight packing ----
    int t = (blk - 2048) * 256 + threadIdx.x;
    if (t < 64 * 576) {
        int o = t / 576, kk = t % 576;
        int k = kk >> 6, c = kk & 63;
        wpackM[t] = __half_as_ushort(__float2half_rn(w[(o * 64 + c) * 9 + k]));
        return;
    }
    t -= 64 * 576;
    if (t < 32 * 576) {
        int o = t / 576, kk = t % 576;
        int k = kk >> 6, c = kk & 63;
        float v = 0.f;
        if (o < 18)      v = w_off[(o * 64 + c) * 9 + k];
        else if (o < 27) v = w_mod[((o - 18) * 64 + c) * 9 + k];
        wpack27[t] = __half_as_ushort(__float2half_rn(v));
        if (kk == 0) bias27[o] = (o < 18) ? b_off[o] : (o < 27 ? b_mod[o - 18] : 0.f);
    }
}

// ---------------------------------------------------------------------------
// Kernel 2 (fused): window-staged conv27 + deformable conv, LDS gathers.
// ---------------------------------------------------------------------------
__global__ __launch_bounds__(256, 2) void deform_main_k(const unsigned short* __restrict__ xt,
                                                        const unsigned short* __restrict__ wpackM,
                                                        const unsigned short* __restrict__ wpack27,
                                                        const float* __restrict__ bias27,
                                                        const float* __restrict__ bias,
                                                        float* __restrict__ out) {
    extern __shared__ __align__(16) char lds[];
    char*           winB = lds;
    unsigned short (*samp)[64][72] = (unsigned short (*)[64][72])(lds + L_SAMP);
    float          (*pp)[28]       = (float (*)[28])(lds + L_SAMP);   // overlays samp (dead then)
    ushort4*        pOff = (ushort4*)(lds + L_POFF);
    uint4*          pW   = (uint4*)(lds + L_PW);

    int blk  = blockIdx.x;                          // 2048 = 8 b * 256
    int b    = blk >> 8;
    int pos0 = (blk & 255) << 6;
    int row  = pos0 >> 7;                           // all 64 positions share one row
    int c0   = pos0 & 127;                          // 0 or 64
    int rbase = row - 2, cbase = c0 - 2;            // window origin
    int tid  = threadIdx.x;
    int lane = tid & 63, wv = tid >> 6;
    int r = lane & 15, q = lane >> 4;
    int pg = lane >> 3;                             // position subgroup 0..7
    int j8 = lane & 7;                              // channel chunk (8 f16 = 16B)

    const unsigned short* xb = xt + ((size_t)b << 20);
    const char* xbb = (const char*)xb;

    // ---- stage window: 5 x 68 positions x 64ch f16, zero-pad, swizzled ----
    // dest chunk jd holds source chunk jd ^ (cc & 7)
    for (int e = tid; e < 2720; e += 256) {         // 2720 = 5*68*8 uint4
        int rr  = e / 544;                          // 544 = 68*8
        int rem = e - rr * 544;
        int cc  = rem >> 3;
        int jd  = rem & 7;
        int sy  = rbase + rr, sx = cbase + cc;
        uint4 v = {0u, 0u, 0u, 0u};
        if (sy >= 0 && sy < 128 && sx >= 0 && sx < 128) {
            int js = jd ^ (cc & 7);
            v = *(const uint4*)&xb[(size_t)(((sy << 7) + sx) << 6) + (js << 3)];
        }
        *(uint4*)(winB + (((rr * 68) + cc) << 7) + (jd << 4)) = v;
    }
    __syncthreads();

    // ---- conv27 from the window (rows 1..3 = row-1..row+1, zero-padded) ----
    {
        floatx4 acc27[2] = {};
        #pragma unroll
        for (int k = 0; k < 9; ++k) {
            int ki = k / 3, kj = k % 3;
            #pragma unroll
            for (int chh = 0; chh < 2; ++chh) {
                half8 a0 = *(const half8*)&wpack27[(r)      * 576 + (k << 6) + (chh << 5) + (q << 3)];
                half8 a1 = *(const half8*)&wpack27[(16 + r) * 576 + (k << 6) + (chh << 5) + (q << 3)];
                int cc = (wv << 4) + r + kj + 1;    // w = c0-1 + (pos + kj)
                int rr = ki + 1;
                int chunk = ((chh << 2) + q) ^ (cc & 7);
                half8 bf = *(const half8*)(winB + (((rr * 68) + cc) << 7) + (chunk << 4));
                acc27[0] = __builtin_amdgcn_mfma_f32_16x16x32_f16(a0, bf, acc27[0], 0, 0, 0);
                acc27[1] = __builtin_amdgcn_mfma_f32_16x16x32_f16(a1, bf, acc27[1], 0, 0, 0);
            }
        }
        #pragma unroll
        for (int s = 0; s < 2; ++s) {
            #pragma unroll
            for (int reg = 0; reg < 4; ++reg) {
                int oc = (s << 4) + (q << 2) + reg;
                if (oc < 27) {
                    float v = acc27[s][reg] + bias27[oc];
                    if (oc >= 18) v = 2.f / (1.f + __expf(-v));
                    pp[(wv << 4) + r][oc] = v;
                }
            }
        }
    }
    __syncthreads();                                // pp visible

    // ---- params: encode corners as window-idx (fast) or 0x8000|pos (slow) ----
    for (int e = tid; e < 576; e += 256) {
        int k = e >> 6, p = e & 63;
        int pos = pos0 + p;
        float dy = pp[p][(k << 1)];
        float dx = pp[p][(k << 1) + 1];
        float m  = pp[p][18 + k];
        float py = (float)(pos >> 7) + (float)(k / 3 - 1) + dy;
        float px = (float)(pos & 127) + (float)(k % 3 - 1) + dx;
        float y0f = floorf(py), x0f = floorf(px);
        int y0 = (int)y0f, x0 = (int)x0f;
        float wy1 = py - y0f, wx1 = px - x0f;
        float wy0 = 1.f - wy1, wx0 = 1.f - wx1;
        bool vy0 = (y0 >= 0) && (y0 < 128);
        bool vy1 = (y0 >= -1) && (y0 < 127);
        bool vx0 = (x0 >= 0) && (x0 < 128);
        bool vx1 = (x0 >= -1) && (x0 < 127);
        float w00 = (vy0 && vx0) ? m * wy0 * wx0 : 0.f;
        float w01 = (vy0 && vx1) ? m * wy0 * wx1 : 0.f;
        float w10 = (vy1 && vx0) ? m * wy1 * wx0 : 0.f;
        float w11 = (vy1 && vx1) ? m * wy1 * wx1 : 0.f;
        int y0c = min(max(y0, 0), 127), y1c = min(max(y0 + 1, 0), 127);
        int x0c = min(max(x0, 0), 127), x1c = min(max(x0 + 1, 0), 127);
        auto enc = [&](int y, int x) -> unsigned short {
            int iy = y - rbase, ix = x - cbase;
            if ((unsigned)iy < 5u && (unsigned)ix < 68u)
                return (unsigned short)((iy * 68 + ix) | ((ix & 7) << 12));
            return (unsigned short)(0x8000u | (unsigned)((y << 7) + x));
        };
        ushort4 io;
        io.x = enc(y0c, x0c);
        io.y = enc(y0c, x1c);
        io.z = enc(y1c, x0c);
        io.w = enc(y1c, x1c);
        pOff[e] = io;
        union { uint4 u; __half2 h[4]; } pw;
        pw.h[0] = __float2half2_rn(w00);
        pw.h[1] = __float2half2_rn(w01);
        pw.h[2] = __float2half2_rn(w10);
        pw.h[3] = __float2half2_rn(w11);
        pW[e] = pw.u;
    }
    __syncthreads();                                // pOff/pW ready; pp dead

    // ---- tap pipeline: LDS gathers, single corner set, 1 barrier/tap ----
    floatx4 acc[4] = {};
    const char* xp = xbb + (j8 << 4);               // global fallback base
    const unsigned short* wrow = wpackM + ((wv << 4) + r) * 576 + (q << 3);

    uint4   c00[2], c01[2], c10[2], c11[2];         // single corner set
    uint4   cw[2];
    ushort4 nio[2];
    uint4   ncw[2];
    half8   afC[2], afN[2];

    auto readParams = [&](int k) {
        #pragma unroll
        for (int i = 0; i < 2; ++i) {
            int e  = (k << 6) + (wv << 4) + (i << 3) + pg;
            nio[i] = pOff[e];
            ncw[i] = pW[e];
        }
    };
    auto ldwin = [&](unsigned int u) -> uint4 {     // fast: LDS window read
        int idx = (int)(u & 0xFFFu);
        int s   = (int)((u >> 12) & 7u);
        return *(const uint4*)(winB + (idx << 7) + ((j8 ^ s) << 4));
    };
    auto ldany = [&](unsigned int u) -> uint4 {     // slow: global gather
        int pos;
        if (u & 0x8000u) pos = (int)(u & 0x7FFFu);
        else {
            int idx = (int)(u & 0xFFFu);
            int iy = idx / 68, ix = idx - iy * 68;
            pos = ((rbase + iy) << 7) + (cbase + ix);
        }
        return *(const uint4*)(xp + ((size_t)pos << 7));
    };
    auto gather = [&]() {                           // corners for staged tap
        unsigned int mm = (unsigned)nio[0].x | nio[0].y | nio[0].z | nio[0].w
                        | nio[1].x | nio[1].y | nio[1].z | nio[1].w;
        if (__all((mm & 0x8000u) == 0)) {
            #pragma unroll
            for (int i = 0; i < 2; ++i) {
                cw[i]  = ncw[i];
                c00[i] = ldwin(nio[i].x);
                c01[i] = ldwin(nio[i].y);
                c10[i] = ldwin(nio[i].z);
                c11[i] = ldwin(nio[i].w);
            }
        } else {
            #pragma unroll
            for (int i = 0; i < 2; ++i) {
                cw[i]  = ncw[i];
                c00[i] = ldany(nio[i].x);
                c01[i] = ldany(nio[i].y);
                c10[i] = ldany(nio[i].z);
                c11[i] = ldany(nio[i].w);
            }
        }
    };
    auto blendStore = [&](int buf) {                // buf compile-time
        #pragma unroll
        for (int i = 0; i < 2; ++i) {
            int p = (wv << 4) + (i << 3) + pg;
            union { uint4 u; __half2 h[4]; } W; W.u = cw[i];
            uint4 o4;
            o4.x = blend2h(c00[i].x, c01[i].x, c10[i].x, c11[i].x, W.h);
            o4.y = blend2h(c00[i].y, c01[i].y, c10[i].y, c11[i].y, W.h);
            o4.z = blend2h(c00[i].z, c01[i].z, c10[i].z, c11[i].z, W.h);
            o4.w = blend2h(c00[i].w, c01[i].w, c10[i].w, c11[i].w, W.h);
            *(uint4*)&samp[buf][p][j8 << 3] = o4;
        }
    };
    auto ldsBarrier = [&]() {
        asm volatile("s_waitcnt lgkmcnt(0)\n\ts_barrier" ::: "memory");
    };

    // prologue: tap 0 blended into samp[0]; params(1) staged
    readParams(0); gather(); blendStore(0);
    readParams(1);
    afC[0] = *(const half8*)&wrow[0];
    afC[1] = *(const half8*)&wrow[32];

    #pragma unroll
    for (int k = 0; k < 9; ++k) {
        if (k < 8) {
            afN[0] = *(const half8*)&wrow[((k + 1) << 6)];
            afN[1] = *(const half8*)&wrow[((k + 1) << 6) + 32];
        }
        ldsBarrier();                               // samp[k&1] complete block-wide
        // B-frags first (their lgkm slots precede the gathers -> fine-grained waits)
        half8 bf[2][4];
        #pragma unroll
        for (int ch = 0; ch < 2; ++ch)
            #pragma unroll
            for (int nt = 0; nt < 4; ++nt)
                bf[ch][nt] = *(const half8*)&samp[k & 1][(nt << 4) + r][(ch << 5) + (q << 3)];
        if (k < 8) gather();                        // tap k+1 corners (LDS), overlap MFMA
        #pragma unroll
        for (int ch = 0; ch < 2; ++ch)
            #pragma unroll
            for (int nt = 0; nt < 4; ++nt)
                acc[nt] = __builtin_amdgcn_mfma_f32_16x16x32_f16(afC[ch], bf[ch][nt], acc[nt], 0, 0, 0);
        if (k < 8) {
            blendStore((k + 1) & 1);                // consumes this body's gathers
            if (k <= 6) readParams(k + 2);
            afC[0] = afN[0];
            afC[1] = afN[1];
        }
    }

    #pragma unroll
    for (int nt = 0; nt < 4; ++nt) {
        #pragma unroll
        for (int reg = 0; reg < 4; ++reg) {
            int oc  = (wv << 4) + (q << 2) + reg;
            int pos = pos0 + (nt << 4) + r;
            float v = acc[nt][reg] + bias[oc];
            out[(size_t)(((b << 6) + oc) << 14) + pos] = fmaxf(v, 0.f);
        }
    }
}

// ---------------------------------------------------------------------------
extern "C" void kernel_launch(void* const* d_in, const int* in_sizes, int n_in,
                              void* d_out, int out_size, void* d_ws, size_t ws_size,
                              hipStream_t stream) {
    const float* data  = (const float*)d_in[0];
    const float* w     = (const float*)d_in[1];
    const float* bias  = (const float*)d_in[2];
    const float* w_off = (const float*)d_in[3];
    const float* b_off = (const float*)d_in[4];
    const float* w_mod = (const float*)d_in[5];
    const float* b_mod = (const float*)d_in[6];
    float* out = (float*)d_out;

    char* ws = (char*)d_ws;
    unsigned short* dataT   = (unsigned short*)(ws + OFF_DATAT);
    unsigned short* wpackM  = (unsigned short*)(ws + OFF_WM);
    unsigned short* wpack27 = (unsigned short*)(ws + OFF_W27);
    float*          bias27  = (float*)(ws + OFF_B27);

    static bool s_attr = false;
    if (!s_attr) {
        hipFuncSetAttribute((const void*)deform_main_k,
                            hipFuncAttributeMaxDynamicSharedMemorySize, L_TOTAL);
        s_attr = true;
    }

    prep_k<<<2264, 256, 0, stream>>>(data, dataT, w, w_off, w_mod,
                                     b_off, b_mod, wpackM, wpack27, bias27);
    deform_main_k<<<2048, 256, L_TOTAL, stream>>>(dataT, wpackM, wpack27,
                                                  bias27, bias, out);
}

// Round 4
// 160.660 us; speedup vs baseline: 1.1549x; 1.1549x over previous
//
#include <hip/hip_runtime.h>
#include <hip/hip_fp16.h>
#include <cstdint>

// ---------------------------------------------------------------------------
// SingleDeformConv on MI355X (gfx950)
// data (8,64,128,128) f32; w (64,64,3,3); b (64); w_off (18,64,3,3); b_off(18);
// w_mod (9,64,3,3); b_mod (9).  out = relu(deform_conv(...)) (8,64,128,128) f32
//
// R14 -> R15: REVERT deform/prep/offP pipeline to R12-exact (best total
// 162.5; R13/R14 fusion+LDS-gather experiments both regressed — gathers
// touch 8 lines/instr, not 64, and were never the bottleneck). Single lever
// this round: conv27_k rewritten LDS-free. Old conv27 (~26us inferred, ~5us
// structural) paid 16-line scattered A-frag loads (72/wave) + staging +
// barrier serialization. New conv27: B-frags read directly from L1/L2-hot
// xt (36 instrs/wave, 9x tap reuse -> L1); A repacked by prep into
// MFMA-native wq[k][chh][s][q][r][8] so each A-frag load is ONE coalesced
// 1KB instruction. No LDS, no barrier -> ~6 blocks/CU resident.
// ---------------------------------------------------------------------------

typedef _Float16 half8 __attribute__((ext_vector_type(8)));
typedef __attribute__((ext_vector_type(4))) float floatx4;

// pack two floats -> f16x2 dword (RNE)
__device__ __forceinline__ unsigned int pack2h(float lo, float hi) {
    __half2 h = __floats2half2_rn(lo, hi);
    union { __half2 h; unsigned int u; } cv; cv.h = h;
    return cv.u;
}
// blend one f16x2 dword from 4 corners with broadcast __half2 weights
__device__ __forceinline__ unsigned int blend2h(unsigned int a, unsigned int b,
                                                unsigned int c, unsigned int d,
                                                const __half2* w) {
    union { unsigned int u; __half2 h; } A, B, C, D, O;
    A.u = a; B.u = b; C.u = c; D.u = d;
    __half2 s = __hmul2(A.h, w[0]);
    s = __hfma2(B.h, w[1], s);
    s = __hfma2(C.h, w[2], s);
    s = __hfma2(D.h, w[3], s);
    O.h = s;
    return O.u;
}

// Workspace layout (bytes) — R12 layout restored
#define OFF_DATAT 0u               // [8][16384][64] f16   = 16777216 B
#define OFF_OFFP  16777216u        // [8][9][3][16384] f32 = 14155776 B (dy,dx,mask)
#define OFF_WM    30932992u        // [64][576] f16        = 73728 B
#define OFF_W27   31006720u        // wq[9][2][2][4][16][8] f16 = 36864 B
#define OFF_B27   31043584u        // [32] f32             = 128 B
// total 31043712 B

// ---------------------------------------------------------------------------
// Kernel 1: prep = NCHW f32 -> NHWC f16 transpose (blocks 0..2047)
//           + weight packing / bias27 (blocks 2048..2263)
// wq layout: per (k, chh, s) a 512-half (1KB) block; within it offset
// q*128 + r*8 + j, where lane(r,q) of the MFMA A-frag reads halves
// [lane*8 .. lane*8+7]  ->  one fully-coalesced 1KB load per (k,chh,s).
// value at (k,chh,s,q,r,j) = W27[oc = s*16+r][c = chh*32+q*8+j][k]
// ---------------------------------------------------------------------------
__global__ __launch_bounds__(256) void prep_k(const float* __restrict__ x,
                                              unsigned short* __restrict__ xt,
                                              const float* __restrict__ w,
                                              const float* __restrict__ w_off,
                                              const float* __restrict__ w_mod,
                                              const float* __restrict__ b_off,
                                              const float* __restrict__ b_mod,
                                              unsigned short* __restrict__ wpackM,
                                              unsigned short* __restrict__ wq,
                                              float* __restrict__ bias27) {
    __shared__ float tile[64][65];
    int blk = blockIdx.x;
    if (blk < 2048) {                              // ---- transpose ----
        int b    = blk >> 8;
        int pos0 = (blk & 255) << 6;
        int lane = threadIdx.x & 63;
        int g    = threadIdx.x >> 6;
        for (int c = g; c < 64; c += 4)
            tile[c][lane] = x[(((b << 6) + c) << 14) + pos0 + lane];
        __syncthreads();
        int c2 = lane & 31;
        for (int i = g; i < 32; i += 4) {
            int pr = (i << 1) + (lane >> 5);
            unsigned int d = pack2h(tile[c2 << 1][pr], tile[(c2 << 1) + 1][pr]);
            *(unsigned int*)&xt[((size_t)((b << 14) + pos0 + pr) << 6) + (c2 << 1)] = d;
        }
        return;
    }
    // ---- weight packing ----
    int t = (blk - 2048) * 256 + threadIdx.x;
    if (t < 64 * 576) {
        int o = t / 576, kk = t % 576;
        int k = kk >> 6, c = kk & 63;
        wpackM[t] = __half_as_ushort(__float2half_rn(w[(o * 64 + c) * 9 + k]));
        return;
    }
    t -= 64 * 576;
    if (t < 32 * 576) {
        int o = t / 576, kk = t % 576;
        int k = kk >> 6, c = kk & 63;
        float v = 0.f;
        if (o < 18)      v = w_off[(o * 64 + c) * 9 + k];
        else if (o < 27) v = w_mod[((o - 18) * 64 + c) * 9 + k];
        // dest: (k, chh=c>>5, s=o>>4, q=(c>>3)&3, r=o&15, j=c&7)
        int s = o >> 4, r = o & 15;
        int chh = c >> 5, q = (c >> 3) & 3, j = c & 7;
        int dst = (((((k << 1) + chh) << 1) + s) << 9) + (q << 7) + (r << 3) + j;
        wq[dst] = __half_as_ushort(__float2half_rn(v));
        if (kk == 0) bias27[o] = (o < 18) ? b_off[o] : (o < 27 ? b_mod[o - 18] : 0.f);
    }
}

// ---------------------------------------------------------------------------
// Kernel 2: offset/mask conv (27 ch, padded to 32) — LDS-free implicit GEMM.
// Block: 256 thr, 2 rows x 64 cols patch. B-frags straight from xt (L1-hot:
// each xt line reused 9x by taps within the block). A-frags one coalesced
// 1KB load each from wq. No LDS, no barriers.
// ---------------------------------------------------------------------------
__global__ __launch_bounds__(256) void conv27_k(const unsigned short* __restrict__ xt,
                                                const unsigned short* __restrict__ wq,
                                                const float* __restrict__ bias27,
                                                float* __restrict__ offP) {
    int blk   = blockIdx.x;                         // 1024 = 8 b * 128 patches
    int b     = blk >> 7;
    int patch = blk & 127;
    int m     = patch >> 1;                         // row pair
    int h     = patch & 1;                          // col half
    int tid   = threadIdx.x;
    int lane  = tid & 63, wv = tid >> 6;
    int r = lane & 15, q = lane >> 4;

    const unsigned short* xb = xt + ((size_t)b << 20);
    int rb  = (m << 1) - 1;                         // top source row of patch
    int cxb = (h << 6) + (wv << 4) + r - 1;         // per-lane source col base
    int chq = (q << 3);                             // lane channel sub-chunk

    floatx4 acc[4] = {};                            // [s*2 + tr]
    #pragma unroll
    for (int k = 0; k < 9; ++k) {
        int ki = k / 3, kj = k % 3;
        #pragma unroll
        for (int chh = 0; chh < 2; ++chh) {
            int abase = ((((k << 1) + chh) << 1) << 9) + (lane << 3);
            half8 a0 = *(const half8*)&wq[abase];           // s=0 block
            half8 a1 = *(const half8*)&wq[abase + 512];     // s=1 block
            #pragma unroll
            for (int tr = 0; tr < 2; ++tr) {
                int sy = rb + tr + ki;
                int sx = cxb + kj;
                half8 bf = {};
                if ((unsigned)sy < 128u && (unsigned)sx < 128u)
                    bf = *(const half8*)&xb[(size_t)(((sy << 7) + sx) << 6) + (chh << 5) + chq];
                acc[0 + tr] = __builtin_amdgcn_mfma_f32_16x16x32_f16(a0, bf, acc[0 + tr], 0, 0, 0);
                acc[2 + tr] = __builtin_amdgcn_mfma_f32_16x16x32_f16(a1, bf, acc[2 + tr], 0, 0, 0);
            }
        }
    }

    #pragma unroll
    for (int s = 0; s < 2; ++s) {
        #pragma unroll
        for (int tr = 0; tr < 2; ++tr) {
            #pragma unroll
            for (int reg = 0; reg < 4; ++reg) {
                int oc = (s << 4) + (q << 2) + reg;
                if (oc >= 27) continue;
                int pos = (((m << 1) + tr) << 7) + (h << 6) + (wv << 4) + r;
                float v = acc[(s << 1) + tr][reg] + bias27[oc];
                int kk, comp;
                if (oc < 18) { kk = oc >> 1; comp = oc & 1; }
                else         { kk = oc - 18; comp = 2; v = 2.f / (1.f + __expf(-v)); }
                offP[(size_t)(((b * 9 + kk) * 3 + comp) << 14) + pos] = v;
            }
        }
    }
}

// ---------------------------------------------------------------------------
// Kernel 3: main deformable conv — R12-exact two-tap pipelined f16 datapath.
// ---------------------------------------------------------------------------
__global__ __launch_bounds__(256, 3) void deform_main_k(const unsigned short* __restrict__ xt,
                                                        const unsigned short* __restrict__ wpackM,
                                                        const float* __restrict__ offP,
                                                        const float* __restrict__ bias,
                                                        float* __restrict__ out) {
    __shared__ ushort4 pOff[576];                   // 4608 B  corner pos-indices
    __shared__ uint4   pW[576];                     // 9216 B  4x f16x2 weights
    __shared__ unsigned short samp[2][64][72];      // 18432 B B-tile (double buf)
    int blk  = blockIdx.x;                          // 2048 = 8 b * 256
    int b    = blk >> 8;
    int pos0 = (blk & 255) << 6;
    int tid  = threadIdx.x;
    int lane = tid & 63, wv = tid >> 6;
    int r = lane & 15, q = lane >> 4;
    int pg = lane >> 3;                             // position subgroup 0..7
    int j8 = lane & 7;                              // channel chunk (8 f16 = 16B)

    const char* xbb = (const char*)(xt + ((size_t)b << 20));

    // ---- phase 0: params, one thread per (tap,pos) entry ----
    for (int e = tid; e < 576; e += 256) {
        int k = e >> 6, p = e & 63;
        int pos = pos0 + p;
        const float* offk = offP + ((size_t)((b * 9 + k) * 3) << 14);
        float dy = offk[pos];
        float dx = offk[16384 + pos];
        float m  = offk[32768 + pos];
        float py = (float)(pos >> 7) + (float)(k / 3 - 1) + dy;
        float px = (float)(pos & 127) + (float)(k % 3 - 1) + dx;
        float y0f = floorf(py), x0f = floorf(px);
        int y0 = (int)y0f, x0 = (int)x0f;
        float wy1 = py - y0f, wx1 = px - x0f;
        float wy0 = 1.f - wy1, wx0 = 1.f - wx1;
        bool vy0 = (y0 >= 0) && (y0 < 128);
        bool vy1 = (y0 >= -1) && (y0 < 127);
        bool vx0 = (x0 >= 0) && (x0 < 128);
        bool vx1 = (x0 >= -1) && (x0 < 127);
        float w00 = (vy0 && vx0) ? m * wy0 * wx0 : 0.f;
        float w01 = (vy0 && vx1) ? m * wy0 * wx1 : 0.f;
        float w10 = (vy1 && vx0) ? m * wy1 * wx0 : 0.f;
        float w11 = (vy1 && vx1) ? m * wy1 * wx1 : 0.f;
        int y0c = min(max(y0, 0), 127), y1c = min(max(y0 + 1, 0), 127);
        int x0c = min(max(x0, 0), 127), x1c = min(max(x0 + 1, 0), 127);
        ushort4 io;
        io.x = (unsigned short)((y0c << 7) + x0c);
        io.y = (unsigned short)((y0c << 7) + x1c);
        io.z = (unsigned short)((y1c << 7) + x0c);
        io.w = (unsigned short)((y1c << 7) + x1c);
        pOff[e] = io;
        union { uint4 u; __half2 h[4]; } pw;
        pw.h[0] = __float2half2_rn(w00);
        pw.h[1] = __float2half2_rn(w01);
        pw.h[2] = __float2half2_rn(w10);
        pw.h[3] = __float2half2_rn(w11);
        pW[e] = pw.u;
    }
    __syncthreads();                                // pOff/pW ready

    floatx4 acc[4] = {};
    const char* xp = xbb + (j8 << 4);               // per-lane channel-chunk base
    const unsigned short* wrow = wpackM + ((wv << 4) + r) * 576 + (q << 3);

    uint4   c00[2][2], c01[2][2], c10[2][2], c11[2][2];  // [set][i]
    uint4   cwS[2][2];                              // weights per set
    ushort4 nio[2];                                 // staged params (next issue)
    uint4   ncw[2];
    half8   afC[2], afN[2];                         // A-frags, current / next

    auto readParams = [&](int k) {
        #pragma unroll
        for (int i = 0; i < 2; ++i) {
            int e  = (k << 6) + (wv << 4) + (i << 3) + pg;
            nio[i] = pOff[e];
            ncw[i] = pW[e];
        }
    };
    auto issueInto = [&](int s) {                   // s is compile-time at all call sites
        #pragma unroll
        for (int i = 0; i < 2; ++i) {
            cwS[s][i] = ncw[i];
            c00[s][i] = *(const uint4*)(xp + ((int)nio[i].x << 7));
            c01[s][i] = *(const uint4*)(xp + ((int)nio[i].y << 7));
            c10[s][i] = *(const uint4*)(xp + ((int)nio[i].z << 7));
            c11[s][i] = *(const uint4*)(xp + ((int)nio[i].w << 7));
        }
    };
    auto blendStore = [&](int s, int buf) {         // s, buf compile-time
        #pragma unroll
        for (int i = 0; i < 2; ++i) {
            int p = (wv << 4) + (i << 3) + pg;
            union { uint4 u; __half2 h[4]; } W; W.u = cwS[s][i];
            uint4 o4;
            o4.x = blend2h(c00[s][i].x, c01[s][i].x, c10[s][i].x, c11[s][i].x, W.h);
            o4.y = blend2h(c00[s][i].y, c01[s][i].y, c10[s][i].y, c11[s][i].y, W.h);
            o4.z = blend2h(c00[s][i].z, c01[s][i].z, c10[s][i].z, c11[s][i].z, W.h);
            o4.w = blend2h(c00[s][i].w, c01[s][i].w, c10[s][i].w, c11[s][i].w, W.h);
            *(uint4*)&samp[buf][p][j8 << 3] = o4;
        }
    };

    // LDS-only barrier: commit this wave's ds_writes (lgkmcnt), then barrier.
    auto ldsBarrier = [&]() {
        asm volatile("s_waitcnt lgkmcnt(0)\n\ts_barrier" ::: "memory");
    };

    // prologue: taps 0 and 1 into the pipe; params(2) staged
    readParams(0); issueInto(0);
    readParams(1); issueInto(1);
    afC[0] = *(const half8*)&wrow[0];
    afC[1] = *(const half8*)&wrow[32];
    blendStore(0, 0);                               // blend tap0 -> samp[0]
    readParams(2);

    #pragma unroll
    for (int k = 0; k < 9; ++k) {
        if (k <= 6) issueInto(k & 1);               // corners for tap k+2
        if (k < 8) {
            afN[0] = *(const half8*)&wrow[((k + 1) << 6)];
            afN[1] = *(const half8*)&wrow[((k + 1) << 6) + 32];
        }
        ldsBarrier();                               // samp[k&1] complete block-wide
        #pragma unroll
        for (int ch = 0; ch < 2; ++ch) {
            #pragma unroll
            for (int nt = 0; nt < 4; ++nt) {
                half8 bfrag = *(const half8*)&samp[k & 1][(nt << 4) + r][(ch << 5) + (q << 3)];
                acc[nt] = __builtin_amdgcn_mfma_f32_16x16x32_f16(afC[ch], bfrag, acc[nt], 0, 0, 0);
            }
        }
        if (k < 8) {
            blendStore((k + 1) & 1, (k + 1) & 1);   // corners issued at body k-1
            if (k <= 5) readParams(k + 3);          // params for issue at body k+1
            afC[0] = afN[0];
            afC[1] = afN[1];
        }
    }

    #pragma unroll
    for (int nt = 0; nt < 4; ++nt) {
        #pragma unroll
        for (int reg = 0; reg < 4; ++reg) {
            int oc  = (wv << 4) + (q << 2) + reg;
            int pos = pos0 + (nt << 4) + r;
            float v = acc[nt][reg] + bias[oc];
            out[(size_t)(((b << 6) + oc) << 14) + pos] = fmaxf(v, 0.f);
        }
    }
}

// ---------------------------------------------------------------------------
extern "C" void kernel_launch(void* const* d_in, const int* in_sizes, int n_in,
                              void* d_out, int out_size, void* d_ws, size_t ws_size,
                              hipStream_t stream) {
    const float* data  = (const float*)d_in[0];
    const float* w     = (const float*)d_in[1];
    const float* bias  = (const float*)d_in[2];
    const float* w_off = (const float*)d_in[3];
    const float* b_off = (const float*)d_in[4];
    const float* w_mod = (const float*)d_in[5];
    const float* b_mod = (const float*)d_in[6];
    float* out = (float*)d_out;

    char* ws = (char*)d_ws;
    unsigned short* dataT   = (unsigned short*)(ws + OFF_DATAT);
    float*          offP    = (float*)(ws + OFF_OFFP);
    unsigned short* wpackM  = (unsigned short*)(ws + OFF_WM);
    unsigned short* wq      = (unsigned short*)(ws + OFF_W27);
    float*          bias27  = (float*)(ws + OFF_B27);

    prep_k<<<2264, 256, 0, stream>>>(data, dataT, w, w_off, w_mod,
                                     b_off, b_mod, wpackM, wq, bias27);
    conv27_k<<<1024, 256, 0, stream>>>(dataT, wq, bias27, offP);
    deform_main_k<<<2048, 256, 0, stream>>>(dataT, wpackM, offP, bias, out);
}